// Round 1
// baseline (1869.545 us; speedup 1.0000x reference)
//
#include <hip/hip_runtime.h>
#include <cstdint>
#include <cstddef>

#define NROWS 32768
#define DDIM  64
#define KDIM  8192
#define KCHUNKS 16              // k-chunks per row-block (one wave each)
#define KPER  (KDIM / KCHUNKS)  // 512 k per wave

// ---- prep: wt[k][d] = w[d][k]; wsq[k] = sum_d w[d][k]^2 ----
__global__ void vq_prep(const float* __restrict__ w,
                        float* __restrict__ wt,
                        float* __restrict__ wsq) {
    int k = blockIdx.x * blockDim.x + threadIdx.x;
    if (k >= KDIM) return;
    float s = 0.f;
#pragma unroll
    for (int d = 0; d < DDIM; ++d) {
        float v = w[(size_t)d * KDIM + k];   // coalesced across lanes (consecutive k)
        wt[(size_t)k * DDIM + d] = v;
        s = fmaf(v, v, s);
    }
    wsq[k] = s;
}

// ---- init per-row argmin keys ----
__global__ void vq_init(unsigned long long* __restrict__ keys) {
    int i = blockIdx.x * blockDim.x + threadIdx.x;
    if (i < NROWS) keys[i] = ~0ull;
}

// ---- fused score + argmin ----
// lane = row within a 64-row block; each wave scans one 512-wide k chunk.
// Block = 256 threads = 4 waves = 4 consecutive k chunks of one row block.
__global__ void __launch_bounds__(256)
vq_score(const float* __restrict__ x,
         const float* __restrict__ wt,
         const float* __restrict__ wsq,
         unsigned long long* __restrict__ keys) {
    const int row_block = blockIdx.x >> 2;          // 512 row blocks
    const int kgroup    = blockIdx.x & 3;           // 4 k-groups per row block
    const int wave      = threadIdx.x >> 6;
    const int lane      = threadIdx.x & 63;
    const int row       = row_block * 64 + lane;
    const int chunk     = kgroup * 4 + wave;        // 0..15
    const int k0        = chunk * KPER;

    // x row -> 64 VGPRs
    float xr[DDIM];
    const float4* xp = (const float4*)(x + (size_t)row * DDIM);
#pragma unroll
    for (int i = 0; i < DDIM / 4; ++i) {
        float4 v = xp[i];
        xr[4 * i + 0] = v.x;
        xr[4 * i + 1] = v.y;
        xr[4 * i + 2] = v.z;
        xr[4 * i + 3] = v.w;
    }

    float best  = __int_as_float(0x7f800000);  // +inf
    int   bestk = k0;

    for (int k = k0; k < k0 + KPER; ++k) {
        const float4* wr = (const float4*)(wt + (size_t)k * DDIM);  // wave-uniform addr
        float a0 = 0.f, a1 = 0.f, a2 = 0.f, a3 = 0.f;
#pragma unroll
        for (int i = 0; i < DDIM / 4; ++i) {
            float4 v = wr[i];
            a0 = fmaf(xr[4 * i + 0], v.x, a0);
            a1 = fmaf(xr[4 * i + 1], v.y, a1);
            a2 = fmaf(xr[4 * i + 2], v.z, a2);
            a3 = fmaf(xr[4 * i + 3], v.w, a3);
        }
        float dot   = (a0 + a1) + (a2 + a3);
        float score = fmaf(-2.f, dot, wsq[k]);  // |x|^2 constant per row -> dropped
        if (score < best) { best = score; bestk = k; }  // strict < => first min
    }

    // monotonic fp32 -> u32 map, pack with k for lowest-k tie-break
    uint32_t u = __float_as_uint(best);
    u = (u & 0x80000000u) ? ~u : (u | 0x80000000u);
    unsigned long long key = ((unsigned long long)u << 32) | (unsigned)bestk;
    atomicMin(&keys[row], key);
}

// ---- gather: out[row][d] = wt[bestk[row]][d] ----
__global__ void vq_gather(const unsigned long long* __restrict__ keys,
                          const float* __restrict__ wt,
                          float* __restrict__ out) {
    int t = blockIdx.x * blockDim.x + threadIdx.x;
    if (t >= NROWS * DDIM) return;
    int row = t >> 6;
    int d   = t & 63;
    int k   = (int)(keys[row] & 0xFFFFFFFFull);
    out[t] = wt[(size_t)k * DDIM + d];
}

extern "C" void kernel_launch(void* const* d_in, const int* in_sizes, int n_in,
                              void* d_out, int out_size, void* d_ws, size_t ws_size,
                              hipStream_t stream) {
    const float* x = (const float*)d_in[0];   // [32768, 64]
    const float* w = (const float*)d_in[1];   // [64, 8192]
    float* out = (float*)d_out;               // [32768, 64]

    // workspace layout
    char* ws = (char*)d_ws;
    float* wt  = (float*)ws;                                  // 8192*64*4 = 2 MiB
    float* wsq = (float*)(ws + (size_t)KDIM * DDIM * 4);      // 32 KiB
    unsigned long long* keys =
        (unsigned long long*)(ws + (size_t)KDIM * DDIM * 4 + KDIM * 4); // 256 KiB

    vq_prep<<<(KDIM + 255) / 256, 256, 0, stream>>>(w, wt, wsq);
    vq_init<<<(NROWS + 255) / 256, 256, 0, stream>>>(keys);
    vq_score<<<(NROWS / 64) * (KCHUNKS / 4), 256, 0, stream>>>(x, wt, wsq, keys);
    vq_gather<<<(NROWS * DDIM + 255) / 256, 256, 0, stream>>>(keys, wt, out);
}

// Round 2
// 474.242 us; speedup vs baseline: 3.9422x; 3.9422x over previous
//
#include <hip/hip_runtime.h>
#include <cstdint>
#include <cstddef>

#define NROWS 32768
#define DDIM  64
#define KDIM  8192
#define BR 128            // rows per block
#define BK 128            // codewords per block

// ---- prep: wt[k][d] = w[d][k] (for fast gather); wsq[k] = sum_d w[d][k]^2 ----
__global__ void vq_prep(const float* __restrict__ w,
                        float* __restrict__ wt,
                        float* __restrict__ wsq) {
    int k = blockIdx.x * blockDim.x + threadIdx.x;
    if (k >= KDIM) return;
    float s = 0.f;
#pragma unroll
    for (int d = 0; d < DDIM; ++d) {
        float v = w[(size_t)d * KDIM + k];   // coalesced across lanes
        wt[(size_t)k * DDIM + d] = v;
        s = fmaf(v, v, s);
    }
    wsq[k] = s;
}

// ---- init per-row argmin keys ----
__global__ void vq_init(unsigned long long* __restrict__ keys) {
    int i = blockIdx.x * blockDim.x + threadIdx.x;
    if (i < NROWS) keys[i] = ~0ull;
}

// ---- fused GEMM + argmin ----
// Block tile: 128 rows x 128 codewords. 4 waves in 2x2 (wave tile 64x64).
// Lane tile: 8 rows x 8 codewords (rg = lane>>3, cg = lane&7).
__global__ void __launch_bounds__(256, 2)
vq_gemm(const float* __restrict__ x,
        const float* __restrict__ w,
        const float* __restrict__ wsq,
        unsigned long long* __restrict__ keys) {
    __shared__ float xT[DDIM][BR];   // 32 KiB, transposed x tile
    __shared__ float wl[DDIM][BK];   // 32 KiB

    const int kblk   = blockIdx.x & (KDIM / BK - 1);   // fast dim: 64 k-blocks
    const int rpanel = blockIdx.x >> 6;
    const int rbase  = rpanel * BR;
    const int kbase  = kblk * BK;
    const int t      = threadIdx.x;

    // ---- stage x transposed: write xT[d][row]; lanes span 64 rows -> all banks, conflict-free
    {
        const int row  = t & 127;
        const int dgrp = t >> 7;     // 0/1
#pragma unroll
        for (int it = 0; it < 8; ++it) {
            const int d0 = (dgrp + it * 2) * 4;
            float4 v = *(const float4*)&x[(size_t)(rbase + row) * DDIM + d0];
            xT[d0 + 0][row] = v.x;
            xT[d0 + 1][row] = v.y;
            xT[d0 + 2][row] = v.z;
            xT[d0 + 3][row] = v.w;
        }
    }
    // ---- stage w tile: coalesced float4 global reads, linear b128 LDS writes
    {
#pragma unroll
        for (int it = 0; it < 8; ++it) {
            const int o4 = t + it * 256;        // float4 index within [64][32]
            const int d  = o4 >> 5;
            const int c4 = (o4 & 31) << 2;
            float4 v = *(const float4*)&w[(size_t)d * KDIM + kbase + c4];
            *(float4*)&wl[d][c4] = v;
        }
    }
    __syncthreads();

    const int wave = t >> 6, lane = t & 63;
    const int rg = lane >> 3, cg = lane & 7;
    const int xoff = (wave >> 1) * 64 + rg * 8;   // row offset within block
    const int coff = (wave & 1) * 64 + cg * 8;    // col offset within block

    float acc[8][8];
#pragma unroll
    for (int i = 0; i < 8; ++i)
#pragma unroll
        for (int j = 0; j < 8; ++j) acc[i][j] = 0.f;

#pragma unroll 4
    for (int d = 0; d < DDIM; ++d) {
        float4 xa = *(const float4*)&xT[d][xoff];
        float4 xb = *(const float4*)&xT[d][xoff + 4];
        float4 wa = *(const float4*)&wl[d][coff];
        float4 wb = *(const float4*)&wl[d][coff + 4];
        float xr[8] = {xa.x, xa.y, xa.z, xa.w, xb.x, xb.y, xb.z, xb.w};
        float wc[8] = {wa.x, wa.y, wa.z, wa.w, wb.x, wb.y, wb.z, wb.w};
#pragma unroll
        for (int i = 0; i < 8; ++i)
#pragma unroll
            for (int j = 0; j < 8; ++j)
                acc[i][j] = fmaf(xr[i], wc[j], acc[i][j]);
    }

    // ---- epilogue: score = wsq[k] - 2*dot (|x|^2 dropped, constant per row)
    const int kc = kbase + coff;
    float4 qa = *(const float4*)&wsq[kc];
    float4 qb = *(const float4*)&wsq[kc + 4];
    float q[8] = {qa.x, qa.y, qa.z, qa.w, qb.x, qb.y, qb.z, qb.w};

#pragma unroll
    for (int i = 0; i < 8; ++i) {
        float best = fmaf(-2.f, acc[i][0], q[0]);
        int   bj   = 0;
#pragma unroll
        for (int j = 1; j < 8; ++j) {
            float s = fmaf(-2.f, acc[i][j], q[j]);
            if (s < best) { best = s; bj = j; }   // strict < => lowest k on ties
        }
        uint32_t u = __float_as_uint(best);
        u = (u & 0x80000000u) ? ~u : (u | 0x80000000u);   // monotonic fp32->u32
        unsigned long long key =
            ((unsigned long long)u << 32) | (unsigned)(kc + bj);
        // min-reduce across the 8 col-group lanes (cg = lane&7)
        {
            unsigned long long o;
            o = __shfl_xor(key, 1); key = (o < key) ? o : key;
            o = __shfl_xor(key, 2); key = (o < key) ? o : key;
            o = __shfl_xor(key, 4); key = (o < key) ? o : key;
        }
        if (cg == 0) atomicMin(&keys[rbase + xoff + i], key);
    }
}

// ---- gather: out[row][d] = wt[bestk[row]][d] ----
__global__ void vq_gather(const unsigned long long* __restrict__ keys,
                          const float* __restrict__ wt,
                          float* __restrict__ out) {
    int t = blockIdx.x * blockDim.x + threadIdx.x;
    if (t >= NROWS * DDIM) return;
    int row = t >> 6;
    int d   = t & 63;
    int k   = (int)(keys[row] & 0xFFFFFFFFull);
    out[t] = wt[(size_t)k * DDIM + d];
}

extern "C" void kernel_launch(void* const* d_in, const int* in_sizes, int n_in,
                              void* d_out, int out_size, void* d_ws, size_t ws_size,
                              hipStream_t stream) {
    const float* x = (const float*)d_in[0];   // [32768, 64]
    const float* w = (const float*)d_in[1];   // [64, 8192]
    float* out = (float*)d_out;               // [32768, 64]

    char* ws = (char*)d_ws;
    float* wt  = (float*)ws;                                   // 2 MiB
    float* wsq = (float*)(ws + (size_t)KDIM * DDIM * 4);       // 32 KiB
    unsigned long long* keys =
        (unsigned long long*)(ws + (size_t)KDIM * DDIM * 4 + KDIM * 4); // 256 KiB

    vq_prep<<<KDIM / 256, 256, 0, stream>>>(w, wt, wsq);
    vq_init<<<NROWS / 256, 256, 0, stream>>>(keys);
    vq_gemm<<<(NROWS / BR) * (KDIM / BK), 256, 0, stream>>>(x, w, wsq, keys);
    vq_gather<<<(NROWS * DDIM + 255) / 256, 256, 0, stream>>>(keys, wt, out);
}